// Round 2
// baseline (171.517 us; speedup 1.0000x reference)
//
#include <hip/hip_runtime.h>
#include <hip/hip_bf16.h>
#include <hip/hip_fp16.h>

// DenseGAT fused kernel for MI355X.
// N=4096 nodes, IN=256, HEADS=8, D=64, C=512.
// logits are rank-1 per head + shared adjacency mask => no QK GEMM needed.
// Only real GEMM: alpha @ H (17.2 GFLOP) via f16 MFMA 16x16x32.
//
// ws layout:
//   Hpack : _Float16 [8][128][4][64][8]  @ 0        (4 MB)  H in B-frag order
//   ddata : float    [8][4096][2]        @ 4MB      (256 KB) {e_dst*log2e, 0.2*e_dst*log2e}
//   esrc  : float    [4096][8]           @ 4MB+256K (128 KB)
//   dmax  : uint     [8]                 @ 4MB+384K (32 B)   order-encoded float max

#define GAT_N 4096
#define GAT_K 256
#define GAT_C 512
#define GAT_H 8
#define L2E 1.4426950408889634f

typedef _Float16 v8h __attribute__((ext_vector_type(8)));
typedef float v4f __attribute__((ext_vector_type(4)));
typedef int v4i __attribute__((ext_vector_type(4)));

static __device__ inline v4f mfma16(v8h a, v8h b, v4f c) {
    return __builtin_amdgcn_mfma_f32_16x16x32_f16(a, b, c, 0, 0, 0);
}

// ---------------- Phase A: projection + e_src/e_dst + Hpack -----------------
// grid 512 = 64 mtiles x 8 heads; block 256 (4 waves of 16 rows each).
__global__ __launch_bounds__(256) void gat_proj(
    const float* __restrict__ x, const float* __restrict__ W,
    const float* __restrict__ asrc, const float* __restrict__ adst,
    _Float16* __restrict__ Hpack, float* __restrict__ ddata,
    float* __restrict__ esrc, unsigned* __restrict__ dmax)
{
    const int bid = blockIdx.x;
    const int head = bid & 7, mtile = bid >> 3;
    const int tid = threadIdx.x;
    const int wv = tid >> 6, l = tid & 63;
    const int dlow = l & 15, q = l >> 4;
    const int rowbase = mtile * 64 + wv * 16;
    const int arow = rowbase + dlow;

    v4f acc[4] = {};
#pragma unroll
    for (int kc = 0; kc < 8; ++kc) {
        const int k0 = kc * 32 + q * 8;
        const float4* ap = (const float4*)(x + (size_t)arow * GAT_K + k0);
        float4 xa = ap[0], xb = ap[1];
        v8h af;
        af[0] = (_Float16)xa.x; af[1] = (_Float16)xa.y; af[2] = (_Float16)xa.z; af[3] = (_Float16)xa.w;
        af[4] = (_Float16)xb.x; af[5] = (_Float16)xb.y; af[6] = (_Float16)xb.z; af[7] = (_Float16)xb.w;
#pragma unroll
        for (int nt = 0; nt < 4; ++nt) {
            const int c = head * 64 + nt * 16 + dlow;
            const float4* bp = (const float4*)(W + (size_t)c * GAT_K + k0);
            float4 wa = bp[0], wb = bp[1];
            v8h bf;
            bf[0] = (_Float16)wa.x; bf[1] = (_Float16)wa.y; bf[2] = (_Float16)wa.z; bf[3] = (_Float16)wa.w;
            bf[4] = (_Float16)wb.x; bf[5] = (_Float16)wb.y; bf[6] = (_Float16)wb.z; bf[7] = (_Float16)wb.w;
            acc[nt] = mfma16(af, bf, acc[nt]);
        }
    }

    // epilogue: e_src/e_dst per output row (C/D layout: row=q*4+r, col=dlow)
    float as[4], ad[4];
#pragma unroll
    for (int nt = 0; nt < 4; ++nt) {
        const int d = nt * 16 + dlow;
        as[nt] = asrc[head * 64 + d];
        ad[nt] = adst[head * 64 + d];
    }
    float es[4], ed[4];
#pragma unroll
    for (int r = 0; r < 4; ++r) {
        float se = 0.f, de = 0.f;
#pragma unroll
        for (int nt = 0; nt < 4; ++nt) { se += acc[nt][r] * as[nt]; de += acc[nt][r] * ad[nt]; }
#pragma unroll
        for (int m = 1; m < 16; m <<= 1) { se += __shfl_xor(se, m); de += __shfl_xor(de, m); }
        es[r] = se; ed[r] = de;
    }
    if (dlow == 0) {
#pragma unroll
        for (int r = 0; r < 4; ++r) {
            const int j = rowbase + q * 4 + r;
            esrc[j * GAT_H + head] = es[r];
            ((float2*)ddata)[(size_t)head * GAT_N + j] = make_float2(ed[r] * L2E, 0.2f * L2E * ed[r]);
        }
        float mx = fmaxf(fmaxf(ed[0], ed[1]), fmaxf(ed[2], ed[3]));
        unsigned u = __float_as_uint(mx);
        unsigned enc = (u & 0x80000000u) ? ~u : (u | 0x80000000u);
        atomicMax(dmax + head, enc);
    }

    // Hpack: element (j, d) -> [head][j>>5][nt][ (p>>3)*16 + dlow ][ p&7 ], p=j&31.
    const int jc = rowbase >> 5;
    const int p16 = rowbase & 16;
#pragma unroll
    for (int nt = 0; nt < 4; ++nt) {
#pragma unroll
        for (int rp = 0; rp < 4; rp += 2) {
            const int p = p16 + q * 4 + rp;
            const int qp = p >> 3, e = p & 7;
            const int lanep = qp * 16 + dlow;
            const size_t idx = ((((size_t)head * 128 + jc) * 4 + nt) * 64 + lanep) * 8 + e;
            union { unsigned u; _Float16 h[2]; } pk;
            pk.h[0] = (_Float16)acc[nt][rp];
            pk.h[1] = (_Float16)acc[nt][rp + 1];
            *(unsigned*)(Hpack + idx) = pk.u;
        }
    }
}

// ---------------- Phase B: fused mask + softmax + alpha@H -------------------
// grid 256 = 128 itiles x 2 head-groups; block 512 (8 waves).
// wave wv: head = hg*4 + (wv>>1), parity (wv&1) takes j-chunks of matching parity.
__global__ __launch_bounds__(512) void gat_attn(
    const int* __restrict__ adj, const _Float16* __restrict__ Hpack,
    const float* __restrict__ ddata, const float* __restrict__ esrc,
    const unsigned* __restrict__ dmax, const float* __restrict__ bias,
    float* __restrict__ out)
{
    // adjf[2][32][132] (33792 B) unioned with xchg[4][64*41] (41984 B)
    __shared__ __align__(16) char smem[4 * 64 * 41 * 4];
    float (*adjf)[32][132] = (float (*)[32][132])smem;
    float* xchg = (float*)smem;

    const int bid = blockIdx.x;
    const int it = bid >> 1, hg = bid & 1;
    const int tid = threadIdx.x;
    const int wv = tid >> 6, l = tid & 63;
    const int head = hg * 4 + (wv >> 1), par = wv & 1;
    const int dlow = l & 15, q = l >> 4;
    const int ibase = it * 32;

    // per-row constants: a1 = (s-M)*log2e, a2 = (0.2s-M)*log2e, M = leaky(s+Dmax)
    const unsigned du = dmax[head];
    const float Dm = __uint_as_float((du & 0x80000000u) ? (du & 0x7fffffffu) : ~du);
    float a1[2], a2[2];
#pragma unroll
    for (int rt = 0; rt < 2; ++rt) {
        const int i = ibase + rt * 16 + dlow;
        const float s = esrc[i * GAT_H + head];
        const float sm = s + Dm;
        const float M = fmaxf(sm, 0.2f * sm);
        a1[rt] = (s - M) * L2E;
        a2[rt] = (0.2f * s - M) * L2E;
    }

    v4f accW[2][4] = {};
    v4f accZ[2] = {};
    v8h ones;
#pragma unroll
    for (int e = 0; e < 8; ++e) ones[e] = (_Float16)1.0f;

    // cooperative stage of adj[32 rows][128 j] as 0.0/1.0 floats
    const int srow = tid >> 4;
    const int sc8 = (tid & 15) * 8;
#define GAT_STAGE(BUF, T) {                                                        \
        const v4i* sp = (const v4i*)(adj + (size_t)(ibase + srow) * GAT_N + (T) * 128 + sc8); \
        v4i v0 = __builtin_nontemporal_load(sp);                                   \
        v4i v1 = __builtin_nontemporal_load(sp + 1);                               \
        float* dr = &adjf[BUF][srow][sc8];                                         \
        dr[0] = (float)v0.x; dr[1] = (float)v0.y; dr[2] = (float)v0.z; dr[3] = (float)v0.w; \
        dr[4] = (float)v1.x; dr[5] = (float)v1.y; dr[6] = (float)v1.z; dr[7] = (float)v1.w; }

    GAT_STAGE(0, 0)
    __syncthreads();

    for (int t = 0; t < 32; ++t) {
        const int buf = t & 1;
        if (t + 1 < 32) GAT_STAGE(buf ^ 1, t + 1)

#pragma unroll
        for (int kc = 0; kc < 2; ++kc) {
            const int k0 = par * 64 + kc * 32;          // offset inside 128-j tile
            const int kg = t * 128 + k0 + q * 8;        // global j of this lane's first element
            const float4* dp = (const float4*)(ddata + ((size_t)head * GAT_N + kg) * 2);
            float4 d0 = dp[0], d1 = dp[1], d2 = dp[2], d3 = dp[3];
            const float4* am0 = (const float4*)&adjf[buf][dlow][k0 + q * 8];
            const float4* am1 = (const float4*)&adjf[buf][dlow + 16][k0 + q * 8];
            float4 m00 = am0[0], m01 = am0[1];
            float4 m10 = am1[0], m11 = am1[1];

            v8h fr0, fr1;
#define GAT_PB(E, DD1, DD2, M0, M1) {                                   \
                float t0 = fmaxf((DD1) + a1[0], (DD2) + a2[0]);         \
                float t1 = fmaxf((DD1) + a1[1], (DD2) + a2[1]);         \
                fr0[E] = (_Float16)(__builtin_amdgcn_exp2f(t0) * (M0)); \
                fr1[E] = (_Float16)(__builtin_amdgcn_exp2f(t1) * (M1)); }
            GAT_PB(0, d0.x, d0.y, m00.x, m10.x)
            GAT_PB(1, d0.z, d0.w, m00.y, m10.y)
            GAT_PB(2, d1.x, d1.y, m00.z, m10.z)
            GAT_PB(3, d1.z, d1.w, m00.w, m10.w)
            GAT_PB(4, d2.x, d2.y, m01.x, m11.x)
            GAT_PB(5, d2.z, d2.w, m01.y, m11.y)
            GAT_PB(6, d3.x, d3.y, m01.z, m11.z)
            GAT_PB(7, d3.z, d3.w, m01.w, m11.w)
#undef GAT_PB

            const int jc = t * 4 + par * 2 + kc;
#pragma unroll
            for (int nt = 0; nt < 4; ++nt) {
                const v8h bf = *(const v8h*)(Hpack + ((((size_t)head * 128 + jc) * 4 + nt) * 64 + l) * 8);
                accW[0][nt] = mfma16(fr0, bf, accW[0][nt]);
                accW[1][nt] = mfma16(fr1, bf, accW[1][nt]);
            }
            accZ[0] = mfma16(fr0, ones, accZ[0]);
            accZ[1] = mfma16(fr1, ones, accZ[1]);
        }
        __syncthreads();
    }
#undef GAT_STAGE

    // combine parity waves via LDS (reuses adj buffer space, post-barrier)
    const int pr = wv >> 1;
    float* xb = xchg + (size_t)pr * (64 * 41) + (size_t)l * 41;
    if (par == 1) {
#pragma unroll
        for (int rt = 0; rt < 2; ++rt) {
#pragma unroll
            for (int nt = 0; nt < 4; ++nt)
#pragma unroll
                for (int r = 0; r < 4; ++r) xb[(rt * 4 + nt) * 4 + r] = accW[rt][nt][r];
#pragma unroll
            for (int r = 0; r < 4; ++r) xb[32 + rt * 4 + r] = accZ[rt][r];
        }
    }
    __syncthreads();
    if (par == 0) {
#pragma unroll
        for (int rt = 0; rt < 2; ++rt) {
            float zi[4];
#pragma unroll
            for (int r = 0; r < 4; ++r) zi[r] = 1.0f / (accZ[rt][r] + xb[32 + rt * 4 + r]);
#pragma unroll
            for (int nt = 0; nt < 4; ++nt) {
                const int col = head * 64 + nt * 16 + dlow;
                const float b = bias[col];
#pragma unroll
                for (int r = 0; r < 4; ++r) {
                    const int row = ibase + rt * 16 + q * 4 + r;
                    out[(size_t)row * GAT_C + col] =
                        (accW[rt][nt][r] + xb[(rt * 4 + nt) * 4 + r]) * zi[r] + b;
                }
            }
        }
    }
}

extern "C" void kernel_launch(void* const* d_in, const int* in_sizes, int n_in,
                              void* d_out, int out_size, void* d_ws, size_t ws_size,
                              hipStream_t stream) {
    const float* x    = (const float*)d_in[0];
    const int*   adj  = (const int*)d_in[1];
    const float* W    = (const float*)d_in[2];
    const float* asrc = (const float*)d_in[3];
    const float* adst = (const float*)d_in[4];
    const float* bias = (const float*)d_in[5];
    float* out = (float*)d_out;

    char* ws = (char*)d_ws;                     // needs ~4.6 MB
    _Float16* Hpack = (_Float16*)ws;
    float* ddata = (float*)(ws + (4u << 20));
    float* esrc  = (float*)(ws + (4u << 20) + (256u << 10));
    unsigned* dmax = (unsigned*)(ws + (4u << 20) + (384u << 10));

    (void)hipMemsetAsync(dmax, 0, 8 * sizeof(unsigned), stream);
    hipLaunchKernelGGL(gat_proj, dim3(512), dim3(256), 0, stream,
                       x, W, asrc, adst, Hpack, ddata, esrc, dmax);
    hipLaunchKernelGGL(gat_attn, dim3(256), dim3(512), 0, stream,
                       adj, Hpack, ddata, esrc, dmax, bias, out);
}